// Round 1
// baseline (7707.802 us; speedup 1.0000x reference)
//
#include <hip/hip_runtime.h>
#include <math.h>

// Problem constants (fixed by setup_inputs)
#define T_LEN 512
#define BATCH 64
#define HID 128
#define G4 512   // 4*HID

__device__ __forceinline__ float sigf(float x) { return 1.0f / (1.0f + __expf(-x)); }

// ---------------------------------------------------------------------------
// C[M,N] = A[M,K] @ W[N,K]^T + bias[N]   (fp32, 128x128 tile, 8x8 microtile)
// Requires M%128==0, N%128==0, K%16==0.
// ---------------------------------------------------------------------------
__global__ __launch_bounds__(256) void gemm_bias(
    const float* __restrict__ A, const float* __restrict__ W,
    const float* __restrict__ bias, float* __restrict__ C,
    int M, int N, int K)
{
    __shared__ __align__(16) float As[16][128];
    __shared__ __align__(16) float Ws[16][128];
    const int tid = threadIdx.x;
    const int m0 = blockIdx.y * 128;
    const int n0 = blockIdx.x * 128;
    const int tx = tid & 15, ty = tid >> 4;
    const int lrow = tid >> 1, lk = (tid & 1) * 8;
    float acc[8][8] = {};
    for (int k0 = 0; k0 < K; k0 += 16) {
        const float* Ap = A + (size_t)(m0 + lrow) * K + k0 + lk;
        const float* Wp = W + (size_t)(n0 + lrow) * K + k0 + lk;
        float4 a0 = *(const float4*)Ap;
        float4 a1 = *(const float4*)(Ap + 4);
        float4 w0 = *(const float4*)Wp;
        float4 w1 = *(const float4*)(Wp + 4);
        __syncthreads();   // previous iteration's LDS reads done
        As[lk+0][lrow]=a0.x; As[lk+1][lrow]=a0.y; As[lk+2][lrow]=a0.z; As[lk+3][lrow]=a0.w;
        As[lk+4][lrow]=a1.x; As[lk+5][lrow]=a1.y; As[lk+6][lrow]=a1.z; As[lk+7][lrow]=a1.w;
        Ws[lk+0][lrow]=w0.x; Ws[lk+1][lrow]=w0.y; Ws[lk+2][lrow]=w0.z; Ws[lk+3][lrow]=w0.w;
        Ws[lk+4][lrow]=w1.x; Ws[lk+5][lrow]=w1.y; Ws[lk+6][lrow]=w1.z; Ws[lk+7][lrow]=w1.w;
        __syncthreads();
        #pragma unroll
        for (int kk = 0; kk < 16; ++kk) {
            float4 av0 = *(const float4*)&As[kk][ty*8];
            float4 av1 = *(const float4*)&As[kk][ty*8+4];
            float4 wv0 = *(const float4*)&Ws[kk][tx*8];
            float4 wv1 = *(const float4*)&Ws[kk][tx*8+4];
            float av[8] = {av0.x,av0.y,av0.z,av0.w,av1.x,av1.y,av1.z,av1.w};
            float wv[8] = {wv0.x,wv0.y,wv0.z,wv0.w,wv1.x,wv1.y,wv1.z,wv1.w};
            #pragma unroll
            for (int i = 0; i < 8; ++i)
                #pragma unroll
                for (int j = 0; j < 8; ++j)
                    acc[i][j] = fmaf(av[i], wv[j], acc[i][j]);
        }
    }
    float bj[8];
    #pragma unroll
    for (int j = 0; j < 8; ++j) bj[j] = bias[n0 + tx*8 + j];
    #pragma unroll
    for (int i = 0; i < 8; ++i) {
        float* cp = C + (size_t)(m0 + ty*8 + i) * N + n0 + tx*8;
        float4 s0 = make_float4(acc[i][0]+bj[0], acc[i][1]+bj[1], acc[i][2]+bj[2], acc[i][3]+bj[3]);
        float4 s1 = make_float4(acc[i][4]+bj[4], acc[i][5]+bj[5], acc[i][6]+bj[6], acc[i][7]+bj[7]);
        *(float4*)cp = s0;
        *(float4*)(cp + 4) = s1;
    }
}

// ---------------------------------------------------------------------------
// LSTM recurrence, one workgroup per batch element.
// X: (T*B, 512) precomputed x@Wih.T + b ; Whh: (512,128) ; Hout: (T*B, 128)
// 512 threads: thread r owns gate row r; Whh row lives in 128 VGPRs.
// ---------------------------------------------------------------------------
__global__ __launch_bounds__(512) void lstm_rec(
    const float* __restrict__ X,
    const float* __restrict__ Whh,
    float* __restrict__ Hout)
{
    const int b = blockIdx.x;
    const int r = threadIdx.x;
    __shared__ __align__(16) float h_s[HID];
    __shared__ float gate_s[G4];
    float w[HID];
    #pragma unroll
    for (int k = 0; k < HID; k += 4) {
        float4 v = *(const float4*)(Whh + (size_t)r * HID + k);
        w[k] = v.x; w[k+1] = v.y; w[k+2] = v.z; w[k+3] = v.w;
    }
    float c = 0.f;
    if (r < HID) h_s[r] = 0.f;
    __syncthreads();
    for (int t = 0; t < T_LEN; ++t) {
        float a0 = X[(size_t)(t * BATCH + b) * G4 + r];
        float a1 = 0.f, a2 = 0.f, a3 = 0.f;
        const float4* h4 = (const float4*)h_s;
        #pragma unroll
        for (int k = 0; k < HID/4; ++k) {
            float4 hv = h4[k];
            a0 = fmaf(w[4*k+0], hv.x, a0);
            a1 = fmaf(w[4*k+1], hv.y, a1);
            a2 = fmaf(w[4*k+2], hv.z, a2);
            a3 = fmaf(w[4*k+3], hv.w, a3);
        }
        gate_s[r] = (a0 + a1) + (a2 + a3);
        __syncthreads();
        if (r < HID) {
            float gi = gate_s[r], gf = gate_s[HID+r], gg = gate_s[2*HID+r], go = gate_s[3*HID+r];
            c = sigf(gf) * c + sigf(gi) * tanhf(gg);
            float h = sigf(go) * tanhf(c);
            h_s[r] = h;
            Hout[(size_t)(t * BATCH + b) * HID + r] = h;
        }
        __syncthreads();
    }
}

// ---------------------------------------------------------------------------
// Decoder: one workgroup per batch element, 64 steps.
// KV: (T, B, 256)  (cols 0..127 = K, 128..255 = V), layout (t*B+b)*256 + j
// ---------------------------------------------------------------------------
__global__ __launch_bounds__(512) void decoder(
    const float* __restrict__ KV,
    const float* __restrict__ attn_w, const float* __restrict__ attn_b,
    const float* __restrict__ ow, const float* __restrict__ ob,
    const float* __restrict__ Wih0, const float* __restrict__ Whh0, const float* __restrict__ b0,
    const float* __restrict__ Wih1, const float* __restrict__ Whh1, const float* __restrict__ b1,
    const float* __restrict__ lw, const float* __restrict__ lb,
    float* __restrict__ Y)
{
    const int b = blockIdx.x;
    const int tid = threadIdx.x;
    __shared__ __align__(16) float out_s[HID];
    __shared__ __align__(16) float q_s[HID];
    __shared__ __align__(16) float sc[4 * T_LEN];
    __shared__ float red[512];
    __shared__ __align__(16) float ctxp[4][HID];
    __shared__ __align__(16) float ctx_s[HID];
    __shared__ __align__(16) float x_s[2 * HID];
    __shared__ __align__(16) float h0_s[HID];
    __shared__ __align__(16) float h1_s[HID];
    __shared__ float gate_s[G4];
    __shared__ float hmax[4], hden[4];
    float c0 = 0.f, c1 = 0.f;
    if (tid < HID) { out_s[tid] = 0.f; h0_s[tid] = 0.f; h1_s[tid] = 0.f; }
    __syncthreads();
    const float scale = 0.17677669529663687f;   // 1/sqrt(32)
    const int g = tid >> 7, l = tid & 127;
    for (int step = 0; step < 64; ++step) {
        // ---- q = (out @ Wq.T + bq) * scale ----
        if (tid < HID) {
            const float* wr = attn_w + (size_t)tid * HID;
            float acc = attn_b[tid];
            #pragma unroll
            for (int k = 0; k < HID; k += 4) {
                float4 wv = *(const float4*)(wr + k);
                float4 ov = *(const float4*)(out_s + k);
                acc += wv.x*ov.x + wv.y*ov.y + wv.z*ov.z + wv.w*ov.w;
            }
            q_s[tid] = acc * scale;
        }
        __syncthreads();
        // ---- scores: thread tid handles t=tid for all 4 heads ----
        {
            const float* kvp = KV + ((size_t)tid * BATCH + b) * 256;
            #pragma unroll
            for (int h = 0; h < 4; ++h) {
                float acc = 0.f;
                #pragma unroll
                for (int d = 0; d < 32; d += 4) {
                    float4 kv4 = *(const float4*)(kvp + h*32 + d);
                    float4 q4  = *(const float4*)(q_s + h*32 + d);
                    acc += kv4.x*q4.x + kv4.y*q4.y + kv4.z*q4.z + kv4.w*q4.w;
                }
                sc[h * T_LEN + tid] = acc;
            }
        }
        __syncthreads();
        // ---- softmax per head; group g (128 threads, 2 waves) owns head g ----
        float v[4];
        float mx = -3.4e38f;
        #pragma unroll
        for (int i = 0; i < 4; ++i) { v[i] = sc[g*T_LEN + l + 128*i]; mx = fmaxf(mx, v[i]); }
        red[tid] = mx;
        __syncthreads();
        if (l < 64) {
            float m2 = fmaxf(red[g*128 + l], red[g*128 + l + 64]);
            #pragma unroll
            for (int s = 32; s > 0; s >>= 1) m2 = fmaxf(m2, __shfl_xor(m2, s, 64));
            if (l == 0) hmax[g] = m2;
        }
        __syncthreads();
        float hm = hmax[g];
        float s4 = 0.f;
        #pragma unroll
        for (int i = 0; i < 4; ++i) {
            float e = __expf(v[i] - hm);
            sc[g*T_LEN + l + 128*i] = e;
            s4 += e;
        }
        red[tid] = s4;
        __syncthreads();
        if (l < 64) {
            float s2 = red[g*128 + l] + red[g*128 + l + 64];
            #pragma unroll
            for (int s = 32; s > 0; s >>= 1) s2 += __shfl_xor(s2, s, 64);
            if (l == 0) hden[g] = s2;
        }
        __syncthreads();
        // ---- ctx[h,d] = sum_t attn * V ----
        {
            const int oi = tid & 127, ch = tid >> 7;
            const int hh = oi >> 5;
            float part = 0.f;
            for (int tt = 0; tt < 128; ++tt) {
                int t = ch * 128 + tt;
                part = fmaf(sc[hh*T_LEN + t], KV[((size_t)t*BATCH + b)*256 + 128 + oi], part);
            }
            ctxp[ch][oi] = part;
        }
        __syncthreads();
        if (tid < HID) {
            float cx = (ctxp[0][tid] + ctxp[1][tid] + ctxp[2][tid] + ctxp[3][tid]) / hden[tid >> 5];
            ctx_s[tid] = cx;
        }
        __syncthreads();
        // ---- ctx out-projection, build x = [out, ctx_proj] ----
        if (tid < HID) {
            const float* wr = ow + (size_t)tid * HID;
            float acc = ob[tid];
            #pragma unroll
            for (int k = 0; k < HID; k += 4) {
                float4 wv = *(const float4*)(wr + k);
                float4 cv = *(const float4*)(ctx_s + k);
                acc += wv.x*cv.x + wv.y*cv.y + wv.z*cv.z + wv.w*cv.w;
            }
            x_s[HID + tid] = acc;
            x_s[tid] = out_s[tid];
        }
        __syncthreads();
        // ---- decoder LSTM layer 0 ----
        {
            const float* wi = Wih0 + (size_t)tid * 256;
            const float* wh = Whh0 + (size_t)tid * HID;
            float acc = b0[tid];
            #pragma unroll
            for (int k = 0; k < 256; k += 4) {
                float4 wv = *(const float4*)(wi + k);
                float4 xv = *(const float4*)(x_s + k);
                acc += wv.x*xv.x + wv.y*xv.y + wv.z*xv.z + wv.w*xv.w;
            }
            #pragma unroll
            for (int k = 0; k < HID; k += 4) {
                float4 wv = *(const float4*)(wh + k);
                float4 hv = *(const float4*)(h0_s + k);
                acc += wv.x*hv.x + wv.y*hv.y + wv.z*hv.z + wv.w*hv.w;
            }
            gate_s[tid] = acc;
        }
        __syncthreads();
        if (tid < HID) {
            float gi = gate_s[tid], gf = gate_s[HID+tid], gg = gate_s[2*HID+tid], go = gate_s[3*HID+tid];
            c0 = sigf(gf) * c0 + sigf(gi) * tanhf(gg);
            h0_s[tid] = sigf(go) * tanhf(c0);
        }
        __syncthreads();
        // ---- decoder LSTM layer 1 ----
        {
            const float* wi = Wih1 + (size_t)tid * HID;
            const float* wh = Whh1 + (size_t)tid * HID;
            float acc = b1[tid];
            #pragma unroll
            for (int k = 0; k < HID; k += 4) {
                float4 wv = *(const float4*)(wi + k);
                float4 hv = *(const float4*)(h0_s + k);
                acc += wv.x*hv.x + wv.y*hv.y + wv.z*hv.z + wv.w*hv.w;
            }
            #pragma unroll
            for (int k = 0; k < HID; k += 4) {
                float4 wv = *(const float4*)(wh + k);
                float4 hv = *(const float4*)(h1_s + k);
                acc += wv.x*hv.x + wv.y*hv.y + wv.z*hv.z + wv.w*hv.w;
            }
            gate_s[tid] = acc;
        }
        __syncthreads();
        if (tid < HID) {
            float gi = gate_s[tid], gf = gate_s[HID+tid], gg = gate_s[2*HID+tid], go = gate_s[3*HID+tid];
            c1 = sigf(gf) * c1 + sigf(gi) * tanhf(gg);
            float h = sigf(go) * tanhf(c1);
            h1_s[tid] = h;
            out_s[tid] = fmaxf(h, 0.f);
        }
        __syncthreads();
        // ---- y = relu(h1) @ lin_w.T + lin_b ----
        if (tid < 3) {
            const float* wr = lw + (size_t)tid * HID;
            float acc = lb[tid];
            #pragma unroll
            for (int k = 0; k < HID; k += 4) {
                float4 wv = *(const float4*)(wr + k);
                float4 ov = *(const float4*)(out_s + k);
                acc += wv.x*ov.x + wv.y*ov.y + wv.z*ov.z + wv.w*ov.w;
            }
            Y[((size_t)step * BATCH + b) * 3 + tid] = acc;
        }
        __syncthreads();
    }
}

// ---------------------------------------------------------------------------
extern "C" void kernel_launch(void* const* d_in, const int* in_sizes, int n_in,
                              void* d_out, int out_size, void* d_ws, size_t ws_size,
                              hipStream_t stream) {
    const float* cnn        = (const float*)d_in[0];
    const float* eWih0      = (const float*)d_in[1];
    const float* eWhh0      = (const float*)d_in[2];
    const float* eb0        = (const float*)d_in[3];
    const float* eWih1      = (const float*)d_in[4];
    const float* eWhh1      = (const float*)d_in[5];
    const float* eb1        = (const float*)d_in[6];
    const float* attn_in_w  = (const float*)d_in[7];
    const float* attn_in_b  = (const float*)d_in[8];
    const float* attn_out_w = (const float*)d_in[9];
    const float* attn_out_b = (const float*)d_in[10];
    const float* dWih0      = (const float*)d_in[11];
    const float* dWhh0      = (const float*)d_in[12];
    const float* db0        = (const float*)d_in[13];
    const float* dWih1      = (const float*)d_in[14];
    const float* dWhh1      = (const float*)d_in[15];
    const float* db1        = (const float*)d_in[16];
    const float* lin_w      = (const float*)d_in[17];
    const float* lin_b      = (const float*)d_in[18];
    float* Y  = (float*)d_out;

    // workspace layout (floats): X (32768*512) | H (32768*128) | KV (32768*256)
    // total = 32768*896*4 B = 112 MiB
    float* ws = (float*)d_ws;
    float* X  = ws;
    float* Hb = X  + (size_t)32768 * 512;
    float* KV = Hb + (size_t)32768 * 128;

    const int M = T_LEN * BATCH;  // 32768

    // encoder layer 0: X0 = cnn @ Wih0^T + b0   (K=1024)
    gemm_bias<<<dim3(512/128, M/128), 256, 0, stream>>>(cnn, eWih0, eb0, X, M, 512, 1024);
    lstm_rec<<<BATCH, 512, 0, stream>>>(X, eWhh0, Hb);
    // encoder layer 1: X1 = H0 @ Wih1^T + b1    (K=128)
    gemm_bias<<<dim3(512/128, M/128), 256, 0, stream>>>(Hb, eWih1, eb1, X, M, 512, 128);
    lstm_rec<<<BATCH, 512, 0, stream>>>(X, eWhh1, Hb);   // Hb now holds enc
    // KV = enc @ [Wk;Wv]^T + [bk;bv]            (N=256, K=128)
    gemm_bias<<<dim3(256/128, M/128), 256, 0, stream>>>(Hb, attn_in_w + 128*128, attn_in_b + 128,
                                                        KV, M, 256, 128);
    // decoder: 64 steps, one WG per batch element
    decoder<<<BATCH, 512, 0, stream>>>(KV, attn_in_w, attn_in_b, attn_out_w, attn_out_b,
                                       dWih0, dWhh0, db0, dWih1, dWhh1, db1,
                                       lin_w, lin_b, Y);
}